// Round 9
// baseline (371.401 us; speedup 1.0000x reference)
//
#include <hip/hip_runtime.h>
#include <stdint.h>

// TopkActivation: per-row top-k (k=64) over H=32768 fp32, scatter into zeros.
//
// Process-and-discard streaming (rounds 1-8 constraint map: persisting the
// row in registers spills, in LDS kills residency, re-reading costs HBM):
//   - one 256-thread block per row, NO launch_bounds min-wave cap (caps
//     caused every catastrophic spill), natural VGPR ~60 -> ~8 blocks/CU
//   - stream loop: load float4 -> ballot-compact candidates (x > 2.25) into
//     LDS -> nontemporal zero-store -> DISCARD value. No barriers inside.
//   - one __syncthreads (vmcnt drain wanted: zeros visible before winner
//     overwrites); 8 co-resident blocks hide each other's drain + tail
//   - exact rank of ~400 candidates (value desc, index asc = jax.lax.top_k
//     tie rule); non-candidates are all < 2.25 < every candidate, so
//     candidate ranks == global ranks when count >= k
//   - count < k or > CAP (17 sigma / 31 sigma for N(0,1) data): exact radix
//     fallback re-reads the row from global. Correct for ANY input.

#define H_DIM    32768
#define NTHREADS 256
#define NITER    (H_DIM / (NTHREADS * 4))   // 32 float4 per thread
#define CAP      1024
#define FCAP     512                        // fallback candidate cap
#define NBINS    4096
#define NWAVES   (NTHREADS / 64)            // 4
#define BPT      (NBINS / NTHREADS)         // 16 bins/thread in fallback scan

typedef float f32x4 __attribute__((ext_vector_type(4)));

__device__ __forceinline__ uint32_t f2mono(float f) {
    uint32_t u = __float_as_uint(f);
    return (u & 0x80000000u) ? ~u : (u | 0x80000000u);
}
__device__ __forceinline__ float mono2f(uint32_t m) {
    uint32_t u = (m & 0x80000000u) ? (m & 0x7fffffffu) : ~m;
    return __uint_as_float(u);
}

__global__ __launch_bounds__(NTHREADS)   // max-threads only; NO min-wave cap
void topk_kernel(const float* __restrict__ in, const int* __restrict__ kp,
                 float* __restrict__ out)
{
    // smem aliasing: fast path uses [0:CAP)=cand_u, [CAP:2*CAP)=cand_i.
    // fallback reuses all 4096 words as hist, then [0:FCAP)+[FCAP:2*FCAP)
    // as its own candidate arrays.
    __shared__ uint32_t smem[NBINS];
    __shared__ uint32_t wave_tot[NWAVES];
    __shared__ uint32_t s_b, s_g, s_cnt, s_ncand;

    const uint32_t t    = threadIdx.x;
    const uint32_t row  = blockIdx.x;
    const uint32_t k    = (uint32_t)kp[0];
    const uint32_t lane = t & 63;
    const uint32_t wid  = t >> 6;

    const f32x4* __restrict__ rin  = (const f32x4*)(in  + (size_t)row * H_DIM);
    f32x4*       __restrict__ rout = (f32x4*)(out + (size_t)row * H_DIM);

    uint32_t* cand_u = smem;
    uint32_t* cand_i = smem + CAP;

    if (t == 0) s_ncand = 0;
    __syncthreads();

    // ---- stream loop: load -> compact candidates -> zero-store -> discard
    const uint32_t TM = f2mono(2.25f);
    const f32x4 z = {0.f, 0.f, 0.f, 0.f};
    #pragma unroll 4
    for (int i = 0; i < NITER; ++i) {
        f32x4 v = __builtin_nontemporal_load(&rin[t + i * NTHREADS]);
        #pragma unroll
        for (int c = 0; c < 4; ++c) {
            uint32_t u = f2mono(v[c]);
            bool cd = u > TM;
            unsigned long long m = __ballot(cd);
            if (m) {                                  // wave-uniform
                uint32_t base = 0;
                if (lane == 0) base = atomicAdd(&s_ncand, (uint32_t)__popcll(m));
                base = (uint32_t)__shfl((int)base, 0);
                if (cd) {
                    uint32_t pos = base + (uint32_t)__popcll(m & ((1ull << lane) - 1ull));
                    if (pos < CAP) {
                        cand_u[pos] = u;
                        cand_i[pos] = (t + (uint32_t)i * NTHREADS) * 4u + (uint32_t)c;
                    }
                }
            }
        }
        __builtin_nontemporal_store(z, &rout[t + i * NTHREADS]);
    }
    // vmcnt(0)+lgkmcnt(0): zero-stores globally retired before winner
    // overwrites; candidates published. 8 blocks/CU hide the drain.
    __syncthreads();

    const uint32_t nc = s_ncand;
    if (nc >= k && nc <= CAP) {
        // ---- fast path: exact rank over candidates, scatter <=k winners
        for (uint32_t i = t; i < nc; i += NTHREADS) {
            uint32_t ui = cand_u[i], ii = cand_i[i];
            uint32_t rank = 0;
            for (uint32_t j = 0; j < nc; ++j) {
                uint32_t uj = cand_u[j];
                rank += (uj > ui || (uj == ui && cand_i[j] < ii)) ? 1u : 0u;
            }
            if (rank < k) out[(size_t)row * H_DIM + ii] = mono2f(ui);
        }
        return;   // block-uniform
    }

    // ================= exact fallback (re-reads row; cold) =================
    #pragma unroll
    for (int i = 0; i < NBINS / NTHREADS; ++i) smem[t + i * NTHREADS] = 0;
    if (t == 0) s_ncand = 0;
    __syncthreads();

    for (int i = 0; i < NITER; ++i) {
        f32x4 v = rin[t + i * NTHREADS];
        #pragma unroll
        for (int c = 0; c < 4; ++c) atomicAdd(&smem[f2mono(v[c]) >> 20], 1u);
    }
    __syncthreads();

    // boundary bin: cumAbove < k <= cumAbove + bin
    {
        uint32_t h[BPT];
        uint32_t s = 0;
        #pragma unroll
        for (int bb = 0; bb < BPT; ++bb) { h[bb] = smem[BPT * t + bb]; s += h[bb]; }
        uint32_t v = s;
        #pragma unroll
        for (int off = 1; off < 64; off <<= 1) {     // inclusive suffix scan
            uint32_t o = __shfl_down(v, off);
            if (lane + off < 64) v += o;
        }
        if (lane == 0) wave_tot[wid] = v;
        __syncthreads();
        uint32_t acc = 0;
        #pragma unroll
        for (int w = 0; w < NWAVES; ++w) if ((uint32_t)w > wid) acc += wave_tot[w];
        const uint32_t Ech = v + acc - s;
        if (Ech < k && k <= Ech + s) {
            uint32_t gl = Ech;
            #pragma unroll
            for (int bb = BPT - 1; bb >= 0; --bb) {
                if (gl + h[bb] >= k) { s_b = BPT * t + (uint32_t)bb; s_g = gl; s_cnt = h[bb]; break; }
                gl += h[bb];
            }
        }
    }
    __syncthreads();

    uint32_t prefix = s_b, g = s_g, cnt = s_cnt, shift = 20;

    while (cnt > FCAP && shift > 0) {
        uint32_t nshift = (shift >= 12) ? (shift - 12) : 0;
        uint32_t nbits  = shift - nshift;
        uint32_t nbins  = 1u << nbits;
        __syncthreads();
        for (uint32_t i2 = t; i2 < nbins; i2 += NTHREADS) smem[i2] = 0;
        __syncthreads();
        for (int i = 0; i < NITER; ++i) {
            f32x4 v = rin[t + i * NTHREADS];
            #pragma unroll
            for (int c = 0; c < 4; ++c) {
                uint32_t u = f2mono(v[c]);
                if ((u >> shift) == prefix)
                    atomicAdd(&smem[(u >> nshift) & (nbins - 1)], 1u);
            }
        }
        __syncthreads();
        if (t == 0) {
            uint32_t gl = g;
            for (int bb = (int)nbins - 1; bb >= 0; --bb) {
                uint32_t hh = smem[bb];
                if (gl + hh >= k) { s_b = (uint32_t)bb; s_g = gl; s_cnt = hh; break; }
                gl += hh;
            }
        }
        __syncthreads();
        prefix = (prefix << nbits) | s_b;
        g = s_g; cnt = s_cnt; shift = nshift;
    }

    const uint32_t need = k - g;

    if (cnt <= FCAP) {
        // write strictly-above values; collect boundary candidates
        uint32_t* fu = smem;
        uint32_t* fi = smem + FCAP;
        for (int i = 0; i < NITER; ++i) {
            f32x4 v = rin[t + i * NTHREADS];
            #pragma unroll
            for (int c = 0; c < 4; ++c) {
                uint32_t u  = f2mono(v[c]);
                uint32_t hi = u >> shift;
                uint32_t ii = (t + (uint32_t)i * NTHREADS) * 4u + (uint32_t)c;
                if (hi > prefix) {
                    out[(size_t)row * H_DIM + ii] = v[c];
                } else if (hi == prefix) {
                    uint32_t p = atomicAdd(&s_ncand, 1u);
                    if (p < FCAP) { fu[p] = u; fi[p] = ii; }
                }
            }
        }
        __syncthreads();
        const uint32_t n2 = s_ncand;
        for (uint32_t i = t; i < n2; i += NTHREADS) {
            uint32_t ui = fu[i], ii = fi[i];
            uint32_t rank = 0;
            for (uint32_t j = 0; j < n2; ++j) {
                uint32_t uj = fu[j];
                rank += (uj > ui || (uj == ui && fi[j] < ii)) ? 1u : 0u;
            }
            if (rank < need) out[(size_t)row * H_DIM + ii] = mono2f(ui);
        }
    } else {
        // tie-flood: shift==0, >FCAP identical boundary keys; first `need`
        // in global index order win. idx = 1024*i + 4*t + c is lexicographic
        // in (i, t, c) -> per-chunk block scan.
        uint32_t base = 0;
        for (int i = 0; i < NITER; ++i) {
            f32x4 v = rin[t + i * NTHREADS];
            uint32_t u4[4], mc[4], m = 0;
            #pragma unroll
            for (int c = 0; c < 4; ++c) {
                u4[c] = f2mono(v[c]);
                mc[c] = m;
                m += (u4[c] == prefix) ? 1u : 0u;
            }
            #pragma unroll
            for (int c = 0; c < 4; ++c)
                if (u4[c] > prefix)
                    out[(size_t)row * H_DIM + (t + (uint32_t)i * NTHREADS) * 4u + (uint32_t)c] = v[c];
            uint32_t pre = m;                        // inclusive scan over t
            #pragma unroll
            for (int off = 1; off < 64; off <<= 1) {
                uint32_t o = __shfl_up(pre, off);
                if (lane >= (uint32_t)off) pre += o;
            }
            if (lane == 63) wave_tot[wid] = pre;
            __syncthreads();
            uint32_t wbase = 0, tot = 0;
            #pragma unroll
            for (int w = 0; w < NWAVES; ++w) {
                if ((uint32_t)w < wid) wbase += wave_tot[w];
                tot += wave_tot[w];
            }
            const uint32_t excl = base + wbase + (pre - m);
            #pragma unroll
            for (int c = 0; c < 4; ++c)
                if (u4[c] == prefix && excl + mc[c] < need)
                    out[(size_t)row * H_DIM + (t + (uint32_t)i * NTHREADS) * 4u + (uint32_t)c] = mono2f(prefix);
            base += tot;
            __syncthreads();
        }
    }
}

extern "C" void kernel_launch(void* const* d_in, const int* in_sizes, int n_in,
                              void* d_out, int out_size, void* d_ws, size_t ws_size,
                              hipStream_t stream)
{
    const float* x  = (const float*)d_in[0];
    const int*   kp = (const int*)d_in[1];
    float* out = (float*)d_out;
    const int B = in_sizes[0] / H_DIM;
    hipLaunchKernelGGL(topk_kernel, dim3(B), dim3(NTHREADS), 0, stream, x, kp, out);
}